// Round 3
// baseline (389.327 us; speedup 1.0000x reference)
//
#include <hip/hip_runtime.h>
#include <math.h>

#define S_DIM 4096
#define B_DIM 128
#define H_DIM 128
#define ROWS  4                      // s-rows per k_scores block
#define NBLK  (S_DIM / ROWS)         // 1024 blocks, each a contiguous 256 KB slab
#define NEG_BIG -1e30f

// ---------------- Kernel A: dWa[b,h] = d@W_a ; p_t[b] = S*sigmoid(tanh(d@W_p)@v_p)
__global__ __launch_bounds__(256) void k_prep(
    const float* __restrict__ d, const float* __restrict__ Wa,
    const float* __restrict__ Wp, const float* __restrict__ vp,
    float* __restrict__ dWa, float* __restrict__ pt)
{
    int b  = blockIdx.x;
    int t  = threadIdx.x;
    int h  = t & 127;
    int kh = t >> 7;                  // 0/1: which k-half
    __shared__ float db[H_DIM];
    if (t < H_DIM) db[t] = d[b * H_DIM + t];
    __syncthreads();
    float aa = 0.f, ap = 0.f;
    int k0 = kh * 64;
    #pragma unroll 8
    for (int k = k0; k < k0 + 64; ++k) {
        float dk = db[k];
        aa = fmaf(dk, Wa[k * H_DIM + h], aa);   // coalesced across h
        ap = fmaf(dk, Wp[k * H_DIM + h], ap);
    }
    __shared__ float paa[256], pap[256];
    paa[t] = aa; pap[t] = ap;
    __syncthreads();
    if (t < H_DIM) {
        float a2 = paa[t] + paa[t + 128];
        float p2 = pap[t] + pap[t + 128];
        dWa[b * H_DIM + t] = a2;
        float r = tanhf(p2) * vp[t];
        #pragma unroll
        for (int o = 1; o < 64; o <<= 1) r += __shfl_xor(r, o);
        __shared__ float red[2];
        if ((t & 63) == 0) red[t >> 6] = r;
        __syncthreads();
        if (t == 0) {
            float sum = red[0] + red[1];
            pt[b] = (float)S_DIM / (1.f + __expf(-sum));   // S * sigmoid
        }
    }
}

// ---------------- Kernel B: contiguous-stream scores + softmax partials + window
// Block = 4 complete s-rows (all 128 b) = contiguous 256 KB of e.
// Iteration j: threads load block-contiguous 4 KB; half-wave (t>>5) computes the
// dot for (s_local = j>>4, b = 8*(j&15) + t/32) via 5-step shuffle reduction.
// Raw scores -> LDS [4][129]; phase 2 (1 thread per b) does max/exp + window.
__global__ __launch_bounds__(256) void k_scores(
    const float* __restrict__ e, const float* __restrict__ dWa,
    const float* __restrict__ pt,
    float* __restrict__ pm, float* __restrict__ pl, float* __restrict__ win)
{
    int blk = blockIdx.x;            // owns s in [4*blk, 4*blk+4)
    int t   = threadIdx.x;
    int hl  = t & 31;
    int hi  = t >> 5;                // 0..7

    __shared__ float sc[ROWS][B_DIM + 1];

    const float4* ebase = (const float4*)e + (size_t)blk * (ROWS * B_DIM * H_DIM / 4) + t;

    float4 ev[8];
    #pragma unroll
    for (int j = 0; j < 8; ++j)
        ev[j] = ebase[(size_t)j * 256];

    #pragma unroll 16
    for (int j = 0; j < 64; ++j) {
        float4 cur = ev[j & 7];
        if (j + 8 < 64) ev[j & 7] = ebase[(size_t)(j + 8) * 256];   // prefetch
        int b = ((j & 15) << 3) + hi;
        float4 wf = ((const float4*)(dWa + (b << 7)))[hl];          // L1/L2 resident
        float v = cur.x * wf.x + cur.y * wf.y + cur.z * wf.z + cur.w * wf.w;
        v += __shfl_xor(v, 1);
        v += __shfl_xor(v, 2);
        v += __shfl_xor(v, 4);
        v += __shfl_xor(v, 8);
        v += __shfl_xor(v, 16);
        if (hl == 0) sc[j >> 4][b] = v;
    }
    __syncthreads();

    if (t < B_DIM) {
        int b = t;
        float r0 = sc[0][b], r1 = sc[1][b], r2 = sc[2][b], r3 = sc[3][b];
        float M = fmaxf(fmaxf(r0, r1), fmaxf(r2, r3));
        float L = __expf(r0 - M) + __expf(r1 - M) + __expf(r2 - M) + __expf(r3 - M);
        pm[(size_t)b * NBLK + blk] = M;
        pl[(size_t)b * NBLK + blk] = L;

        float ptb = pt[b];
        int   s0  = (int)floorf(ptb) - 2;
        float rv[ROWS] = {r0, r1, r2, r3};
        #pragma unroll
        for (int i = 0; i < ROWS; ++i) {
            int s = blk * ROWS + i;
            int idx = s - s0;
            if (idx >= 0 && idx < 5) {
                float diff = ptb - (float)s;
                if (fabsf(diff) <= 2.0f) win[b * 5 + idx] = rv[i];
            }
        }
    }
}

// ---------------- Kernel C: combine 1024 partials -> (M,L); w window -> d_out;
// context from <=5 e-rows; output = tanh([ctx, d] @ W_c). 256 threads per b.
__global__ __launch_bounds__(256) void k_final(
    const float* __restrict__ e, const float* __restrict__ d,
    const float* __restrict__ Wc,
    const float* __restrict__ pm, const float* __restrict__ pl,
    const float* __restrict__ win, const float* __restrict__ pt,
    float* __restrict__ out)
{
    int b = blockIdx.x;
    int t = threadIdx.x;

    __shared__ float sh[2];     // M, L
    __shared__ float wv[5];
    __shared__ float x[2 * H_DIM];
    __shared__ float part[2][H_DIM];
    __shared__ float wm[4], wl[4];

    // combine 1024 (m,l) partials: 4 per thread (coalesced), butterfly, LDS
    {
        float m = NEG_BIG, l = 0.f;
        #pragma unroll
        for (int k = 0; k < 4; ++k) {
            float mm = pm[(size_t)b * NBLK + t + 256 * k];
            float ll = pl[(size_t)b * NBLK + t + 256 * k];
            float M2 = fmaxf(m, mm);
            l = l * __expf(m - M2) + ll * __expf(mm - M2);
            m = M2;
        }
        #pragma unroll
        for (int o = 1; o < 64; o <<= 1) {
            float mo = __shfl_xor(m, o);
            float lo = __shfl_xor(l, o);
            float M2 = fmaxf(m, mo);
            l = l * __expf(m - M2) + lo * __expf(mo - M2);
            m = M2;
        }
        if ((t & 63) == 0) { wm[t >> 6] = m; wl[t >> 6] = l; }
        __syncthreads();
        if (t == 0) {
            float M2 = fmaxf(fmaxf(wm[0], wm[1]), fmaxf(wm[2], wm[3]));
            float L2 = 0.f;
            #pragma unroll
            for (int j = 0; j < 4; ++j) L2 += wl[j] * __expf(wm[j] - M2);
            sh[0] = M2; sh[1] = L2;
        }
    }
    __syncthreads();
    float M = sh[0], L = sh[1];
    float ptb = pt[b];
    int   s0  = (int)floorf(ptb) - 2;

    if (t < 5) {
        int s = s0 + t;
        float v = 0.f;
        if (s >= 0 && s < S_DIM) {
            float diff = ptb - (float)s;
            if (fabsf(diff) <= 2.0f) {
                v = __expf(win[b * 5 + t] - M) / L * __expf(-0.5f * diff * diff);
                out[B_DIM * H_DIM + (size_t)s * B_DIM + b] = v;   // w (rest memset 0)
            }
        }
        wv[t] = v;
    }
    __syncthreads();

    if (t < H_DIM) {
        float ctx = 0.f;
        #pragma unroll
        for (int k = 0; k < 5; ++k) {
            int s = s0 + k;
            if (s >= 0 && s < S_DIM)
                ctx = fmaf(wv[k], e[(size_t)s * (B_DIM * H_DIM) + b * H_DIM + t], ctx);
        }
        x[t] = ctx;
    } else {
        x[t] = d[b * H_DIM + (t - H_DIM)];
    }
    __syncthreads();

    int h  = t & 127;
    int jh = t >> 7;                 // 0/1: which j-half
    float acc = 0.f;
    int j0 = jh * H_DIM;
    #pragma unroll 8
    for (int j = j0; j < j0 + H_DIM; ++j)
        acc = fmaf(x[j], Wc[j * H_DIM + h], acc);   // coalesced across h
    part[jh][h] = acc;
    __syncthreads();
    if (t < H_DIM)
        out[b * H_DIM + t] = tanhf(part[0][t] + part[1][t]);
}

extern "C" void kernel_launch(void* const* d_in, const int* in_sizes, int n_in,
                              void* d_out, int out_size, void* d_ws, size_t ws_size,
                              hipStream_t stream)
{
    const float* e  = (const float*)d_in[0];
    const float* d  = (const float*)d_in[1];
    const float* Wa = (const float*)d_in[2];
    const float* Wp = (const float*)d_in[3];
    const float* vp = (const float*)d_in[4];
    const float* Wc = (const float*)d_in[5];
    float* out = (float*)d_out;

    float* ws  = (float*)d_ws;
    float* dWa = ws;                        // B*H        = 16384
    float* pt  = ws + 16384;                // B          = 128
    float* pm  = ws + 16512;                // B*NBLK     = 131072
    float* pl  = ws + 147584;               // B*NBLK     = 131072
    float* win = ws + 278656;               // B*5        = 640

    // zero the w output region [S,B]; window entries are scattered in by k_final
    hipMemsetAsync(out + B_DIM * H_DIM, 0, (size_t)S_DIM * B_DIM * sizeof(float), stream);

    k_prep  <<<B_DIM, 256, 0, stream>>>(d, Wa, Wp, vp, dWa, pt);
    k_scores<<<NBLK, 256, 0, stream>>>(e, dWa, pt, pm, pl, win);
    k_final <<<B_DIM, 256, 0, stream>>>(e, d, Wc, pm, pl, win, pt, out);
}

// Round 4
// 378.597 us; speedup vs baseline: 1.0283x; 1.0283x over previous
//
#include <hip/hip_runtime.h>
#include <math.h>

#define S_DIM 4096
#define B_DIM 128
#define H_DIM 128
#define NBLK  32
#define CHUNK (S_DIM / NBLK)   // 128 s-positions per k_scores block
#define NEG_BIG -1e30f

// ---------------- Kernel A: dWa[b,h] = d@W_a ; p_t[b] = S*sigmoid(tanh(d@W_p)@v_p)
// Also zeroes this block's 16 KB slice of the w output (replaces hipMemsetAsync).
__global__ __launch_bounds__(256) void k_prep(
    const float* __restrict__ d, const float* __restrict__ Wa,
    const float* __restrict__ Wp, const float* __restrict__ vp,
    float* __restrict__ dWa, float* __restrict__ pt, float* __restrict__ w_out)
{
    int b  = blockIdx.x;
    int t  = threadIdx.x;
    int h  = t & 127;
    int kh = t >> 7;                  // 0/1: which k-half
    __shared__ float db[H_DIM];
    __shared__ float paa[256], pap[256];
    __shared__ float red[2];

    if (t < H_DIM) db[t] = d[b * H_DIM + t];
    __syncthreads();

    float aa = 0.f, ap = 0.f;
    int k0 = kh * 64;
    #pragma unroll 8
    for (int k = k0; k < k0 + 64; ++k) {
        float dk = db[k];
        aa = fmaf(dk, Wa[k * H_DIM + h], aa);   // coalesced across h
        ap = fmaf(dk, Wp[k * H_DIM + h], ap);
    }
    paa[t] = aa; pap[t] = ap;
    __syncthreads();

    if (t < H_DIM) {
        float a2 = paa[t] + paa[t + 128];
        float p2 = pap[t] + pap[t + 128];
        dWa[b * H_DIM + t] = a2;
        float r = tanhf(p2) * vp[t];
        #pragma unroll
        for (int o = 1; o < 64; o <<= 1) r += __shfl_xor(r, o);
        if ((t & 63) == 0) red[t >> 6] = r;
    }

    // zero this block's contiguous 16 KB slice of w ([S,B] region of d_out)
    {
        float4* wz = (float4*)(w_out) + b * (S_DIM * B_DIM / B_DIM / 4);  // 1024 float4/block
        #pragma unroll
        for (int k = 0; k < 4; ++k)
            wz[t + 256 * k] = make_float4(0.f, 0.f, 0.f, 0.f);
    }

    __syncthreads();
    if (t == 0) {
        float sum = red[0] + red[1];
        pt[b] = (float)S_DIM / (1.f + __expf(-sum));   // S * sigmoid
    }
}

// ---------------- Kernel B: scores + softmax partials + window-score capture
// grid: (B_DIM, NBLK), block 256 (8 half-waves). Each half-wave owns 16 s-rows,
// issues ALL 16 float4 loads up front, then 16 independent dot+reduce chains,
// one max tree, 16 independent exps, one sum.
__global__ __launch_bounds__(256) void k_scores(
    const float* __restrict__ e, const float* __restrict__ dWa,
    const float* __restrict__ pt,
    float* __restrict__ pm, float* __restrict__ pl, float* __restrict__ win)
{
    int b    = blockIdx.x;
    int blk  = blockIdx.y;
    int tid  = threadIdx.x;
    int wave = tid >> 6;
    int lane = tid & 63;
    int half = lane >> 5;
    int hl   = lane & 31;
    int halfIdx = wave * 2 + half;          // 0..7

    float4 wf = ((const float4*)(dWa + b * H_DIM))[hl];
    float ptb = pt[b];
    int   s0  = (int)floorf(ptb) - 2;

    int sbase = blk * CHUNK + halfIdx;      // s = sbase + 8*j, j = 0..15
    const float* ep = e + (size_t)sbase * (B_DIM * H_DIM) + b * H_DIM + hl * 4;
    const size_t stride8 = (size_t)8 * B_DIM * H_DIM;

    float4 ev[16];
    #pragma unroll
    for (int j = 0; j < 16; ++j)
        ev[j] = *(const float4*)(ep + (size_t)j * stride8);   // 16 loads in flight

    float v[16];
    #pragma unroll
    for (int j = 0; j < 16; ++j)
        v[j] = ev[j].x * wf.x + ev[j].y * wf.y + ev[j].z * wf.z + ev[j].w * wf.w;

    // 16 independent 5-step butterfly reductions within each 32-lane half
    #pragma unroll
    for (int o = 1; o < 32; o <<= 1) {
        #pragma unroll
        for (int j = 0; j < 16; ++j)
            v[j] += __shfl_xor(v[j], o);
    }

    float M = v[0];
    #pragma unroll
    for (int j = 1; j < 16; ++j) M = fmaxf(M, v[j]);
    float L = 0.f;
    #pragma unroll
    for (int j = 0; j < 16; ++j) L += __expf(v[j] - M);   // independent exps

    if (hl == 0) {
        #pragma unroll
        for (int j = 0; j < 16; ++j) {
            int s = sbase + 8 * j;
            int idx = s - s0;
            if (idx >= 0 && idx < 5) {
                float diff = ptb - (float)s;
                if (fabsf(diff) <= 2.0f) win[b * 5 + idx] = v[j];
            }
        }
    }

    __shared__ float ms[8], ls[8];
    if (hl == 0) { ms[halfIdx] = M; ls[halfIdx] = L; }
    __syncthreads();
    if (tid == 0) {
        float Mb = NEG_BIG;
        #pragma unroll
        for (int j = 0; j < 8; ++j) Mb = fmaxf(Mb, ms[j]);
        float Lb = 0.f;
        #pragma unroll
        for (int j = 0; j < 8; ++j) Lb += ls[j] * __expf(ms[j] - Mb);
        pm[b * NBLK + blk] = Mb;
        pl[b * NBLK + blk] = Lb;
    }
}

// ---------------- Kernel C: combine partials -> (M,L); w window -> d_out;
// context from <=5 e-rows; output = tanh([ctx, d] @ W_c).
__global__ __launch_bounds__(256) void k_final(
    const float* __restrict__ e, const float* __restrict__ d,
    const float* __restrict__ Wc,
    const float* __restrict__ pm, const float* __restrict__ pl,
    const float* __restrict__ win, const float* __restrict__ pt,
    float* __restrict__ out)
{
    int b = blockIdx.x;
    int t = threadIdx.x;

    __shared__ float sh[2];     // M, L
    __shared__ float wv[5];
    __shared__ float x[2 * H_DIM];
    __shared__ float part[2][H_DIM];

    if (t < 64) {
        float m = (t < NBLK) ? pm[b * NBLK + t] : NEG_BIG;
        float l = (t < NBLK) ? pl[b * NBLK + t] : 0.f;
        float M = m;
        #pragma unroll
        for (int o = 1; o < 64; o <<= 1) M = fmaxf(M, __shfl_xor(M, o));
        float ls = l * __expf(m - M);
        #pragma unroll
        for (int o = 1; o < 64; o <<= 1) ls += __shfl_xor(ls, o);
        if (t == 0) { sh[0] = M; sh[1] = ls; }
    }
    __syncthreads();
    float M = sh[0], L = sh[1];
    float ptb = pt[b];
    int   s0  = (int)floorf(ptb) - 2;

    if (t < 5) {
        int s = s0 + t;
        float v = 0.f;
        if (s >= 0 && s < S_DIM) {
            float diff = ptb - (float)s;
            if (fabsf(diff) <= 2.0f) {
                v = __expf(win[b * 5 + t] - M) / L * __expf(-0.5f * diff * diff);
                out[B_DIM * H_DIM + (size_t)s * B_DIM + b] = v;   // w (rest zeroed)
            }
        }
        wv[t] = v;
    }
    __syncthreads();

    if (t < H_DIM) {
        float ctx = 0.f;
        #pragma unroll
        for (int k = 0; k < 5; ++k) {
            int s = s0 + k;
            if (s >= 0 && s < S_DIM)
                ctx = fmaf(wv[k], e[(size_t)s * (B_DIM * H_DIM) + b * H_DIM + t], ctx);
        }
        x[t] = ctx;
    } else {
        x[t] = d[b * H_DIM + (t - H_DIM)];
    }
    __syncthreads();

    int h  = t & 127;
    int jh = t >> 7;                 // 0/1: which j-half
    float acc = 0.f;
    int j0 = jh * H_DIM;
    #pragma unroll 8
    for (int j = j0; j < j0 + H_DIM; ++j)
        acc = fmaf(x[j], Wc[j * H_DIM + h], acc);   // coalesced across h
    part[jh][h] = acc;
    __syncthreads();
    if (t < H_DIM)
        out[b * H_DIM + t] = tanhf(part[0][t] + part[1][t]);
}

extern "C" void kernel_launch(void* const* d_in, const int* in_sizes, int n_in,
                              void* d_out, int out_size, void* d_ws, size_t ws_size,
                              hipStream_t stream)
{
    const float* e  = (const float*)d_in[0];
    const float* d  = (const float*)d_in[1];
    const float* Wa = (const float*)d_in[2];
    const float* Wp = (const float*)d_in[3];
    const float* vp = (const float*)d_in[4];
    const float* Wc = (const float*)d_in[5];
    float* out = (float*)d_out;

    float* ws  = (float*)d_ws;
    float* dWa = ws;                        // B*H   = 16384
    float* pt  = ws + 16384;                // B     = 128
    float* pm  = ws + 16512;                // B*NBLK= 4096
    float* pl  = ws + 20608;                // B*NBLK= 4096
    float* win = ws + 24704;                // B*5   = 640

    // k_prep also zeroes the w output region (out + B*H, S*B floats)
    k_prep  <<<B_DIM, 256, 0, stream>>>(d, Wa, Wp, vp, dWa, pt, out + B_DIM * H_DIM);
    k_scores<<<dim3(B_DIM, NBLK), 256, 0, stream>>>(e, dWa, pt, pm, pl, win);
    k_final <<<B_DIM, 256, 0, stream>>>(e, d, Wc, pm, pl, win, pt, out);
}